// Round 5
// baseline (322.280 us; speedup 1.0000x reference)
//
#include <hip/hip_runtime.h>
#include <stdint.h>

#define HIDDEN 2560
#define NHEADS 8
#define HD 512
#define QDIM (NHEADS * HD)        // 4096
#define QKVROWS (QDIM + 2 * HD)   // 5120
#define SEQ 32768
#define CHUNK 64
#define NCHUNK (SEQ / CHUNK)      // 512
#define SCALE 0.044194173824159216f // 1/sqrt(512)

// ws layout (floats):
//   [0 .. 5120)        q[4096], k[512], v[512]
//   [8192 .. 12296)    num[8*512] + den[8]  (atomic accumulator, zeroed by kernel 1)
#define WS_QKV 0
#define WS_K   4096
#define WS_V   4608
#define WS_NUM 8192
#define WS_DEN (WS_NUM + QDIM)     // 12288
#define ACC_FLOATS (QDIM + NHEADS) // 4104

// ---------------- kernel 1: q/k/v GEMV (wave per row) + accumulator zeroing ----------------
__global__ __launch_bounds__(256) void qkv_gemv(
    const float* __restrict__ x,
    const float* __restrict__ wq,
    const float* __restrict__ wk,
    const float* __restrict__ wv,
    float* __restrict__ ws) {
  if (blockIdx.x == QKVROWS / 4) {   // extra block: zero num/den accumulator
    for (int i = threadIdx.x; i < ACC_FLOATS; i += 256) ws[WS_NUM + i] = 0.f;
    return;
  }
  const int row = blockIdx.x * 4 + (threadIdx.x >> 6);
  const int lane = threadIdx.x & 63;
  const float* w;
  if (row < QDIM) w = wq + (size_t)row * HIDDEN;
  else if (row < QDIM + HD) w = wk + (size_t)(row - QDIM) * HIDDEN;
  else w = wv + (size_t)(row - QDIM - HD) * HIDDEN;
  float acc = 0.f;
#pragma unroll
  for (int i = 0; i < 5; i++) {
    const int j = i * 512 + lane * 8;
    float4 a0 = *(const float4*)(w + j);
    float4 a1 = *(const float4*)(w + j + 4);
    float4 b0 = *(const float4*)(x + j);
    float4 b1 = *(const float4*)(x + j + 4);
    acc += a0.x * b0.x + a0.y * b0.y + a0.z * b0.z + a0.w * b0.w +
           a1.x * b1.x + a1.y * b1.y + a1.z * b1.z + a1.w * b1.w;
  }
#pragma unroll
  for (int off = 32; off > 0; off >>= 1) acc += __shfl_xor(acc, off);
  if (lane == 0) ws[WS_QKV + row] = acc;
}

// ---------- kernel 2: attention partials, atomically accumulated ----------
// 512 blocks x 256 threads (CHUNK=64). Phase A: 4 positions/iter (8 float4
// loads in flight before the shuffle chains). Phase C result is atomicAdd'ed
// into the global num/den accumulator — no partial buffer, no reduce kernel.
__global__ __launch_bounds__(256) void attn_partial(
    const float* __restrict__ kvfull,
    float* __restrict__ ws,
    const int* __restrict__ cur_pos) {
  __shared__ float sc[CHUNK][NHEADS];      // exp(score)
  __shared__ float4 vtmp[NHEADS][128];     // 16 KB combine buffer for phase C
  const int tid = threadIdx.x;
  const int lane = tid & 63;
  const int wid = tid >> 6;
  const int cur = cur_pos[0];
  const int s0 = blockIdx.x * CHUNK;
  const float* K = kvfull;
  const float* V = kvfull + (size_t)SEQ * HD;

  // q fragments: lane holds q[h][lane*8 .. +8] for all 8 heads
  float qf[NHEADS][8];
#pragma unroll
  for (int h = 0; h < NHEADS; h++) {
    float4 a = *(const float4*)(ws + WS_QKV + h * HD + lane * 8);
    float4 b = *(const float4*)(ws + WS_QKV + h * HD + lane * 8 + 4);
    qf[h][0] = a.x; qf[h][1] = a.y; qf[h][2] = a.z; qf[h][3] = a.w;
    qf[h][4] = b.x; qf[h][5] = b.y; qf[h][6] = b.z; qf[h][7] = b.w;
  }

  // phase A: exp(scores). wave w handles 16 consecutive positions, 4 per iter.
  // scores are O(1) -> exp without max subtraction is numerically safe.
  for (int ii = 0; ii < 4; ii++) {
    const int sx = wid * 16 + ii * 4;
    float4 A[4], B[4];
#pragma unroll
    for (int u = 0; u < 4; u++) {
      const int s = s0 + sx + u;
      const float* kr = (s == cur) ? (ws + WS_K) : (K + (size_t)s * HD);
      A[u] = *(const float4*)(kr + lane * 8);
      B[u] = *(const float4*)(kr + lane * 8 + 4);
    }
    float p[4][NHEADS];
#pragma unroll
    for (int u = 0; u < 4; u++) {
      const float kb[8] = {A[u].x, A[u].y, A[u].z, A[u].w,
                           B[u].x, B[u].y, B[u].z, B[u].w};
#pragma unroll
      for (int h = 0; h < NHEADS; h++) {
        float t = 0.f;
#pragma unroll
        for (int e = 0; e < 8; e++) t += kb[e] * qf[h][e];
        p[u][h] = t;
      }
    }
#pragma unroll
    for (int off = 32; off > 0; off >>= 1) {
#pragma unroll
      for (int u = 0; u < 4; u++) {
#pragma unroll
        for (int h = 0; h < NHEADS; h++) p[u][h] += __shfl_xor(p[u][h], off);
      }
    }
    if (lane == 0) {
#pragma unroll
      for (int u = 0; u < 4; u++) {
#pragma unroll
        for (int h = 0; h < NHEADS; h++) sc[sx + u][h] = __expf(p[u][h] * SCALE);
      }
    }
  }
  __syncthreads();

  // den: per-head sum of exp -> atomic accumulate
  if (tid < NHEADS) {
    float lsum = 0.f;
    for (int s = 0; s < CHUNK; s++) lsum += sc[s][tid];
    atomicAdd(ws + WS_DEN + tid, lsum);
  }

  // phase C: num = sum exp(s)*V. 128 threads own 4 dims; 2 sy-halves (g)
  const int g = tid >> 7;      // 0,1
  const int tl = tid & 127;
  const int d0 = tl * 4;
  float4 acc[NHEADS];
#pragma unroll
  for (int h = 0; h < NHEADS; h++) acc[h] = make_float4(0.f, 0.f, 0.f, 0.f);
  for (int sy = g * (CHUNK / 2); sy < (g + 1) * (CHUNK / 2); sy++) {
    const int s = s0 + sy;
    const float* vrow = (s == cur) ? (ws + WS_V) : (V + (size_t)s * HD);
    float4 v4 = *(const float4*)(vrow + d0);
#pragma unroll
    for (int h = 0; h < NHEADS; h++) {
      const float pp = sc[sy][h];
      acc[h].x += pp * v4.x; acc[h].y += pp * v4.y;
      acc[h].z += pp * v4.z; acc[h].w += pp * v4.w;
    }
  }
  if (g == 1) {
#pragma unroll
    for (int h = 0; h < NHEADS; h++) vtmp[h][tl] = acc[h];
  }
  __syncthreads();
  if (g == 0) {
#pragma unroll
    for (int h = 0; h < NHEADS; h++) {
      float4 o = vtmp[h][tl];
      o.x += acc[h].x; o.y += acc[h].y; o.z += acc[h].z; o.w += acc[h].w;
      float* dst = ws + WS_NUM + h * HD + d0;
      atomicAdd(dst + 0, o.x);
      atomicAdd(dst + 1, o.y);
      atomicAdd(dst + 2, o.z);
      atomicAdd(dst + 3, o.w);
    }
  }
}

// ---------------- kernel 3: output GEMV with inline normalization ----------------
// Row-loop iteration i spans exactly head i (512 floats), so normalization is
// a single scalar divide per iteration.
__global__ __launch_bounds__(256) void out_gemv(
    const float* __restrict__ wo,
    const float* __restrict__ ws,
    float* __restrict__ out) {
  const int row = blockIdx.x * 4 + (threadIdx.x >> 6);
  const int lane = threadIdx.x & 63;
  const float* w = wo + (size_t)row * QDIM;
  const float* num = ws + WS_NUM;
  const float* den = ws + WS_DEN;
  float acc = 0.f;
#pragma unroll
  for (int i = 0; i < 8; i++) {
    const int j = i * 512 + lane * 8;
    float4 w0 = *(const float4*)(w + j);
    float4 w1 = *(const float4*)(w + j + 4);
    float4 a0 = *(const float4*)(num + j);
    float4 a1 = *(const float4*)(num + j + 4);
    float t = w0.x * a0.x + w0.y * a0.y + w0.z * a0.z + w0.w * a0.w +
              w1.x * a1.x + w1.y * a1.y + w1.z * a1.z + w1.w * a1.w;
    acc += t / den[i];
  }
#pragma unroll
  for (int off = 32; off > 0; off >>= 1) acc += __shfl_xor(acc, off);
  if (lane == 0) out[row] = acc;
}

extern "C" void kernel_launch(void* const* d_in, const int* in_sizes, int n_in,
                              void* d_out, int out_size, void* d_ws, size_t ws_size,
                              hipStream_t stream) {
  (void)in_sizes; (void)n_in; (void)out_size; (void)ws_size;
  const float* x      = (const float*)d_in[0];
  // d_in[1] = kv_sliding (unused by reference)
  const float* kvfull = (const float*)d_in[2];
  const float* wq     = (const float*)d_in[3];
  const float* wk     = (const float*)d_in[4];
  const float* wv     = (const float*)d_in[5];
  const float* wo     = (const float*)d_in[6];
  const int* cur_pos  = (const int*)d_in[7];
  // d_in[8] = ring_pos (unused by reference)
  float* out = (float*)d_out;
  float* ws = (float*)d_ws;

  qkv_gemv<<<QKVROWS / 4 + 1, 256, 0, stream>>>(x, wq, wk, wv, ws);
  attn_partial<<<NCHUNK, 256, 0, stream>>>(kvfull, ws, cur_pos);
  out_gemv<<<HIDDEN / 4, 256, 0, stream>>>(wo, ws, out);
}

// Round 6
// 280.448 us; speedup vs baseline: 1.1492x; 1.1492x over previous
//
#include <hip/hip_runtime.h>
#include <stdint.h>

#define HIDDEN 2560
#define NHEADS 8
#define HD 512
#define QDIM (NHEADS * HD)        // 4096
#define SEQ 32768
#define CHUNK 64
#define NCHUNK (SEQ / CHUNK)      // 512
#define PART_ST (8 + NHEADS * HD) // 4104 floats per partial block: den[8] + num[8][512]
#define SCALE 0.044194173824159216f // 1/sqrt(512)

// ws layout (floats):
//   [0 .. 5120)      q[4096], k[512], v[512]
//   [8192 .. 12288)  attn
//   [16384 .. )      partials: NCHUNK x PART_ST  (~8.4 MiB; ws is 512 MiB)
#define WS_QKV 0
#define WS_K   4096
#define WS_V   4608
#define WS_ATT 8192
#define WS_PART 16384

// ---------------- kernel 1: q/k/v GEMV (wave per row) ----------------
__global__ __launch_bounds__(256) void qkv_gemv(
    const float* __restrict__ x,
    const float* __restrict__ wq,
    const float* __restrict__ wk,
    const float* __restrict__ wv,
    float* __restrict__ qkv) {
  const int row = blockIdx.x * 4 + (threadIdx.x >> 6);
  const int lane = threadIdx.x & 63;
  const float* w;
  if (row < QDIM) w = wq + (size_t)row * HIDDEN;
  else if (row < QDIM + HD) w = wk + (size_t)(row - QDIM) * HIDDEN;
  else w = wv + (size_t)(row - QDIM - HD) * HIDDEN;
  float acc = 0.f;
#pragma unroll
  for (int i = 0; i < 5; i++) {
    const int j = i * 512 + lane * 8;
    float4 a0 = *(const float4*)(w + j);
    float4 a1 = *(const float4*)(w + j + 4);
    float4 b0 = *(const float4*)(x + j);
    float4 b1 = *(const float4*)(x + j + 4);
    acc += a0.x * b0.x + a0.y * b0.y + a0.z * b0.z + a0.w * b0.w +
           a1.x * b1.x + a1.y * b1.y + a1.z * b1.z + a1.w * b1.w;
  }
#pragma unroll
  for (int off = 32; off > 0; off >>= 1) acc += __shfl_xor(acc, off);
  if (lane == 0) qkv[row] = acc;
}

// ---------- kernel 2: attention partials — merged single-pass ----------
// Wave = 16 positions, lane = 8-dim slice. Per position: K-slice + V-slice
// loaded together (4 float4 in flight), 64-lane butterfly puts the score in
// ALL lanes, then acc[h] += p[h]*Vslice in registers. K and V streams issue
// uniformly through the whole kernel (no phase barrier until the final
// 4-wave LDS combine).
__global__ __launch_bounds__(256) void attn_partial(
    const float* __restrict__ kvfull,
    const float* __restrict__ ws,
    const int* __restrict__ cur_pos,
    float* __restrict__ part) {
  __shared__ float accbuf[4][NHEADS * HD]; // 64 KB: per-wave num partials
  __shared__ float denbuf[4][NHEADS];
  const int tid = threadIdx.x;
  const int lane = tid & 63;
  const int wid = tid >> 6;
  const int cur = cur_pos[0];
  const int s0 = blockIdx.x * CHUNK + wid * 16;   // wave's 16 positions
  const float* K = kvfull;
  const float* V = kvfull + (size_t)SEQ * HD;

  // q fragments: lane holds q[h][lane*8 .. +8] for all 8 heads (16 KB, L2-hot)
  float qf[NHEADS][8];
#pragma unroll
  for (int h = 0; h < NHEADS; h++) {
    float4 a = *(const float4*)(ws + WS_QKV + h * HD + lane * 8);
    float4 b = *(const float4*)(ws + WS_QKV + h * HD + lane * 8 + 4);
    qf[h][0] = a.x; qf[h][1] = a.y; qf[h][2] = a.z; qf[h][3] = a.w;
    qf[h][4] = b.x; qf[h][5] = b.y; qf[h][6] = b.z; qf[h][7] = b.w;
  }

  float acc[NHEADS][8];
#pragma unroll
  for (int h = 0; h < NHEADS; h++)
#pragma unroll
    for (int e = 0; e < 8; e++) acc[h][e] = 0.f;
  float den[NHEADS];
#pragma unroll
  for (int h = 0; h < NHEADS; h++) den[h] = 0.f;

#pragma unroll 2
  for (int u = 0; u < 16; u++) {
    const int s = s0 + u;
    const float* kr = (s == cur) ? (ws + WS_K) : (K + (size_t)s * HD);
    const float* vr = (s == cur) ? (ws + WS_V) : (V + (size_t)s * HD);
    float4 k0 = *(const float4*)(kr + lane * 8);
    float4 k1 = *(const float4*)(kr + lane * 8 + 4);
    float4 v0 = *(const float4*)(vr + lane * 8);
    float4 v1 = *(const float4*)(vr + lane * 8 + 4);
    const float kb[8] = {k0.x, k0.y, k0.z, k0.w, k1.x, k1.y, k1.z, k1.w};
    float p[NHEADS];
#pragma unroll
    for (int h = 0; h < NHEADS; h++) {
      float t = 0.f;
#pragma unroll
      for (int e = 0; e < 8; e++) t += kb[e] * qf[h][e];
      p[h] = t;
    }
    // full butterfly: every lane ends with the complete dot product
#pragma unroll
    for (int off = 32; off > 0; off >>= 1) {
#pragma unroll
      for (int h = 0; h < NHEADS; h++) p[h] += __shfl_xor(p[h], off);
    }
#pragma unroll
    for (int h = 0; h < NHEADS; h++) {
      const float pe = __expf(p[h] * SCALE);   // scores O(1): no max needed
      den[h] += pe;
      acc[h][0] += pe * v0.x; acc[h][1] += pe * v0.y;
      acc[h][2] += pe * v0.z; acc[h][3] += pe * v0.w;
      acc[h][4] += pe * v1.x; acc[h][5] += pe * v1.y;
      acc[h][6] += pe * v1.z; acc[h][7] += pe * v1.w;
    }
  }

  // per-wave partials -> LDS
#pragma unroll
  for (int h = 0; h < NHEADS; h++) {
    float4 lo = make_float4(acc[h][0], acc[h][1], acc[h][2], acc[h][3]);
    float4 hi = make_float4(acc[h][4], acc[h][5], acc[h][6], acc[h][7]);
    *(float4*)(&accbuf[wid][h * HD + lane * 8])     = lo;
    *(float4*)(&accbuf[wid][h * HD + lane * 8 + 4]) = hi;
  }
  if (lane == 0) {
#pragma unroll
    for (int h = 0; h < NHEADS; h++) denbuf[wid][h] = den[h];
  }
  __syncthreads();

  // combine 4 waves, write one partial per block (round-0 layout)
  float* pb = part + (size_t)blockIdx.x * PART_ST;
  if (tid < NHEADS)
    pb[tid] = denbuf[0][tid] + denbuf[1][tid] + denbuf[2][tid] + denbuf[3][tid];
  for (int i = tid; i < QDIM / 4; i += 256) {
    float4 a = *(float4*)(&accbuf[0][i * 4]);
    float4 b = *(float4*)(&accbuf[1][i * 4]);
    float4 c = *(float4*)(&accbuf[2][i * 4]);
    float4 d = *(float4*)(&accbuf[3][i * 4]);
    a.x += b.x + c.x + d.x; a.y += b.y + c.y + d.y;
    a.z += b.z + c.z + d.z; a.w += b.w + c.w + d.w;
    *(float4*)(pb + 8 + i * 4) = a;
  }
}

// ---------------- kernel 3: combine partials (pure sum, no rescale) ----------------
__global__ __launch_bounds__(256) void attn_reduce(
    const float* __restrict__ part,
    float* __restrict__ attn) {
  const int h = blockIdx.x >> 4;       // 8 heads
  const int dgrp = blockIdx.x & 15;    // 16 groups of 32 dims
  const int tid = threadIdx.x;
  __shared__ float red[256];
  __shared__ float pacc[8][32];

  red[tid] = part[(size_t)tid * PART_ST + h] + part[(size_t)(tid + 256) * PART_ST + h];
  __syncthreads();
  for (int off = 128; off > 0; off >>= 1) {
    if (tid < off) red[tid] += red[tid + off];
    __syncthreads();
  }
  const float Linv = 1.f / red[0];

  const int dloc = tid & 31;
  const int bs = tid >> 5;             // 8 b-groups of 64
  const int d = dgrp * 32 + dloc;
  float acc = 0.f;
#pragma unroll 8
  for (int b = bs * (NCHUNK / 8); b < (bs + 1) * (NCHUNK / 8); b++) {
    acc += part[(size_t)b * PART_ST + 8 + h * HD + d];
  }
  pacc[bs][dloc] = acc;
  __syncthreads();
  if (tid < 32) {
    float s = ((pacc[0][tid] + pacc[1][tid]) + (pacc[2][tid] + pacc[3][tid])) +
              ((pacc[4][tid] + pacc[5][tid]) + (pacc[6][tid] + pacc[7][tid]));
    attn[h * HD + dgrp * 32 + tid] = s * Linv;
  }
}

// ---------------- kernel 4: output GEMV (wave per row) ----------------
__global__ __launch_bounds__(256) void out_gemv(
    const float* __restrict__ wo,
    const float* __restrict__ attn,
    float* __restrict__ out) {
  const int row = blockIdx.x * 4 + (threadIdx.x >> 6);
  const int lane = threadIdx.x & 63;
  const float* w = wo + (size_t)row * QDIM;
  float acc = 0.f;
#pragma unroll
  for (int i = 0; i < 8; i++) {
    const int j = i * 512 + lane * 8;
    float4 w0 = *(const float4*)(w + j);
    float4 w1 = *(const float4*)(w + j + 4);
    float4 a0 = *(const float4*)(attn + j);
    float4 a1 = *(const float4*)(attn + j + 4);
    acc += w0.x * a0.x + w0.y * a0.y + w0.z * a0.z + w0.w * a0.w +
           w1.x * a1.x + w1.y * a1.y + w1.z * a1.z + w1.w * a1.w;
  }
#pragma unroll
  for (int off = 32; off > 0; off >>= 1) acc += __shfl_xor(acc, off);
  if (lane == 0) out[row] = acc;
}

extern "C" void kernel_launch(void* const* d_in, const int* in_sizes, int n_in,
                              void* d_out, int out_size, void* d_ws, size_t ws_size,
                              hipStream_t stream) {
  (void)in_sizes; (void)n_in; (void)out_size; (void)ws_size;
  const float* x      = (const float*)d_in[0];
  // d_in[1] = kv_sliding (unused by reference)
  const float* kvfull = (const float*)d_in[2];
  const float* wq     = (const float*)d_in[3];
  const float* wk     = (const float*)d_in[4];
  const float* wv     = (const float*)d_in[5];
  const float* wo     = (const float*)d_in[6];
  const int* cur_pos  = (const int*)d_in[7];
  // d_in[8] = ring_pos (unused by reference)
  float* out = (float*)d_out;
  float* ws = (float*)d_ws;

  qkv_gemv<<<(QDIM + 2 * HD) / 4, 256, 0, stream>>>(x, wq, wk, wv, ws + WS_QKV);
  attn_partial<<<NCHUNK, 256, 0, stream>>>(kvfull, ws, cur_pos, ws + WS_PART);
  attn_reduce<<<NHEADS * 16, 256, 0, stream>>>(ws + WS_PART, ws + WS_ATT);
  out_gemv<<<HIDDEN / 4, 256, 0, stream>>>(wo, ws + WS_ATT, out);
}

// Round 7
// 279.648 us; speedup vs baseline: 1.1525x; 1.0029x over previous
//
#include <hip/hip_runtime.h>
#include <stdint.h>

#define HIDDEN 2560
#define NHEADS 8
#define HD 512
#define QDIM (NHEADS * HD)        // 4096
#define SEQ 32768
#define CHUNK 64
#define NCHUNK (SEQ / CHUNK)      // 512
#define PART_ST (8 + NHEADS * HD) // 4104 floats per partial block: den[8] + num[8][512]
#define SCALE 0.044194173824159216f // 1/sqrt(512)

// ws layout (floats):
//   [0 .. 5120)      q[4096], k[512], v[512]
//   [8192 .. 12288)  attn
//   [16384 .. )      partials: NCHUNK x PART_ST  (~8.4 MiB; ws is 512 MiB)
#define WS_QKV 0
#define WS_K   4096
#define WS_V   4608
#define WS_ATT 8192
#define WS_PART 16384

// ---------------- kernel 1: q/k/v GEMV (wave per row) ----------------
__global__ __launch_bounds__(256) void qkv_gemv(
    const float* __restrict__ x,
    const float* __restrict__ wq,
    const float* __restrict__ wk,
    const float* __restrict__ wv,
    float* __restrict__ qkv) {
  const int row = blockIdx.x * 4 + (threadIdx.x >> 6);
  const int lane = threadIdx.x & 63;
  const float* w;
  if (row < QDIM) w = wq + (size_t)row * HIDDEN;
  else if (row < QDIM + HD) w = wk + (size_t)(row - QDIM) * HIDDEN;
  else w = wv + (size_t)(row - QDIM - HD) * HIDDEN;
  float acc = 0.f;
#pragma unroll
  for (int i = 0; i < 5; i++) {
    const int j = i * 512 + lane * 8;
    float4 a0 = *(const float4*)(w + j);
    float4 a1 = *(const float4*)(w + j + 4);
    float4 b0 = *(const float4*)(x + j);
    float4 b1 = *(const float4*)(x + j + 4);
    acc += a0.x * b0.x + a0.y * b0.y + a0.z * b0.z + a0.w * b0.w +
           a1.x * b1.x + a1.y * b1.y + a1.z * b1.z + a1.w * b1.w;
  }
#pragma unroll
  for (int off = 32; off > 0; off >>= 1) acc += __shfl_xor(acc, off);
  if (lane == 0) qkv[row] = acc;
}

// ---------- kernel 2: attention partials — merged single-pass, slim LDS ----------
// Wave = 16 positions, lane = 8-dim slice. K/V for position u+1 prefetched
// before processing u, so 8 float4 loads are in flight across the shuffle/exp
// dependency stretch. Combine buffer is 16 KB (2 heads per round x 4 rounds)
// so LDS no longer caps occupancy at 2 blocks/CU.
__global__ __launch_bounds__(256) void attn_partial(
    const float* __restrict__ kvfull,
    const float* __restrict__ ws,
    const int* __restrict__ cur_pos,
    float* __restrict__ part) {
  __shared__ float accbuf[4][2 * HD];      // 16 KB: per-wave, 2 heads per round
  __shared__ float denbuf[4][NHEADS];
  const int tid = threadIdx.x;
  const int lane = tid & 63;
  const int wid = tid >> 6;
  const int cur = cur_pos[0];
  const int s0 = blockIdx.x * CHUNK + wid * 16;   // wave's 16 positions
  const float* K = kvfull;
  const float* V = kvfull + (size_t)SEQ * HD;

  // q fragments: lane holds q[h][lane*8 .. +8] for all 8 heads (16 KB, L2-hot)
  float qf[NHEADS][8];
#pragma unroll
  for (int h = 0; h < NHEADS; h++) {
    float4 a = *(const float4*)(ws + WS_QKV + h * HD + lane * 8);
    float4 b = *(const float4*)(ws + WS_QKV + h * HD + lane * 8 + 4);
    qf[h][0] = a.x; qf[h][1] = a.y; qf[h][2] = a.z; qf[h][3] = a.w;
    qf[h][4] = b.x; qf[h][5] = b.y; qf[h][6] = b.z; qf[h][7] = b.w;
  }

  float acc[NHEADS][8];
#pragma unroll
  for (int h = 0; h < NHEADS; h++)
#pragma unroll
    for (int e = 0; e < 8; e++) acc[h][e] = 0.f;
  float den[NHEADS];
#pragma unroll
  for (int h = 0; h < NHEADS; h++) den[h] = 0.f;

  // prefetch position 0
  const float* kr0 = (s0 == cur) ? (ws + WS_K) : (K + (size_t)s0 * HD);
  const float* vr0 = (s0 == cur) ? (ws + WS_V) : (V + (size_t)s0 * HD);
  float4 k0 = *(const float4*)(kr0 + lane * 8);
  float4 k1 = *(const float4*)(kr0 + lane * 8 + 4);
  float4 v0 = *(const float4*)(vr0 + lane * 8);
  float4 v1 = *(const float4*)(vr0 + lane * 8 + 4);

  for (int u = 0; u < 16; u++) {
    // issue next position's loads before touching this one's data
    float4 nk0, nk1, nv0, nv1;
    if (u < 15) {
      const int sn = s0 + u + 1;
      const float* krn = (sn == cur) ? (ws + WS_K) : (K + (size_t)sn * HD);
      const float* vrn = (sn == cur) ? (ws + WS_V) : (V + (size_t)sn * HD);
      nk0 = *(const float4*)(krn + lane * 8);
      nk1 = *(const float4*)(krn + lane * 8 + 4);
      nv0 = *(const float4*)(vrn + lane * 8);
      nv1 = *(const float4*)(vrn + lane * 8 + 4);
    }
    const float kb[8] = {k0.x, k0.y, k0.z, k0.w, k1.x, k1.y, k1.z, k1.w};
    float p[NHEADS];
#pragma unroll
    for (int h = 0; h < NHEADS; h++) {
      float t = 0.f;
#pragma unroll
      for (int e = 0; e < 8; e++) t += kb[e] * qf[h][e];
      p[h] = t;
    }
    // full butterfly: every lane ends with the complete dot product
#pragma unroll
    for (int off = 32; off > 0; off >>= 1) {
#pragma unroll
      for (int h = 0; h < NHEADS; h++) p[h] += __shfl_xor(p[h], off);
    }
#pragma unroll
    for (int h = 0; h < NHEADS; h++) {
      const float pe = __expf(p[h] * SCALE);   // scores O(1): no max needed
      den[h] += pe;
      acc[h][0] += pe * v0.x; acc[h][1] += pe * v0.y;
      acc[h][2] += pe * v0.z; acc[h][3] += pe * v0.w;
      acc[h][4] += pe * v1.x; acc[h][5] += pe * v1.y;
      acc[h][6] += pe * v1.z; acc[h][7] += pe * v1.w;
    }
    k0 = nk0; k1 = nk1; v0 = nv0; v1 = nv1;
  }

  if (lane == 0) {
#pragma unroll
    for (int h = 0; h < NHEADS; h++) denbuf[wid][h] = den[h];
  }

  // combine 4 waves' accumulators, 2 heads per round (16 KB LDS reused 4x)
  float* pb = part + (size_t)blockIdx.x * PART_ST;
#pragma unroll
  for (int r = 0; r < 4; r++) {
    const int h0 = r * 2;
#pragma unroll
    for (int hh = 0; hh < 2; hh++) {
      float4 lo = make_float4(acc[h0 + hh][0], acc[h0 + hh][1],
                              acc[h0 + hh][2], acc[h0 + hh][3]);
      float4 hi = make_float4(acc[h0 + hh][4], acc[h0 + hh][5],
                              acc[h0 + hh][6], acc[h0 + hh][7]);
      *(float4*)(&accbuf[wid][hh * HD + lane * 8])     = lo;
      *(float4*)(&accbuf[wid][hh * HD + lane * 8 + 4]) = hi;
    }
    __syncthreads();
    // 256 threads sum 1024 floats (one float4 each) across the 4 waves
    {
      const int i = tid * 4;
      float4 a = *(float4*)(&accbuf[0][i]);
      float4 b = *(float4*)(&accbuf[1][i]);
      float4 c = *(float4*)(&accbuf[2][i]);
      float4 d = *(float4*)(&accbuf[3][i]);
      a.x += b.x + c.x + d.x; a.y += b.y + c.y + d.y;
      a.z += b.z + c.z + d.z; a.w += b.w + c.w + d.w;
      *(float4*)(pb + 8 + h0 * HD + i) = a;
    }
    __syncthreads();
  }
  if (tid < NHEADS)
    pb[tid] = denbuf[0][tid] + denbuf[1][tid] + denbuf[2][tid] + denbuf[3][tid];
}

// ---------------- kernel 3: combine partials (pure sum, no rescale) ----------------
__global__ __launch_bounds__(256) void attn_reduce(
    const float* __restrict__ part,
    float* __restrict__ attn) {
  const int h = blockIdx.x >> 4;       // 8 heads
  const int dgrp = blockIdx.x & 15;    // 16 groups of 32 dims
  const int tid = threadIdx.x;
  __shared__ float red[256];
  __shared__ float pacc[8][32];

  red[tid] = part[(size_t)tid * PART_ST + h] + part[(size_t)(tid + 256) * PART_ST + h];
  __syncthreads();
  for (int off = 128; off > 0; off >>= 1) {
    if (tid < off) red[tid] += red[tid + off];
    __syncthreads();
  }
  const float Linv = 1.f / red[0];

  const int dloc = tid & 31;
  const int bs = tid >> 5;             // 8 b-groups of 64
  const int d = dgrp * 32 + dloc;
  float acc = 0.f;
#pragma unroll 8
  for (int b = bs * (NCHUNK / 8); b < (bs + 1) * (NCHUNK / 8); b++) {
    acc += part[(size_t)b * PART_ST + 8 + h * HD + d];
  }
  pacc[bs][dloc] = acc;
  __syncthreads();
  if (tid < 32) {
    float s = ((pacc[0][tid] + pacc[1][tid]) + (pacc[2][tid] + pacc[3][tid])) +
              ((pacc[4][tid] + pacc[5][tid]) + (pacc[6][tid] + pacc[7][tid]));
    attn[h * HD + dgrp * 32 + tid] = s * Linv;
  }
}

// ---------------- kernel 4: output GEMV (wave per row) ----------------
__global__ __launch_bounds__(256) void out_gemv(
    const float* __restrict__ wo,
    const float* __restrict__ attn,
    float* __restrict__ out) {
  const int row = blockIdx.x * 4 + (threadIdx.x >> 6);
  const int lane = threadIdx.x & 63;
  const float* w = wo + (size_t)row * QDIM;
  float acc = 0.f;
#pragma unroll
  for (int i = 0; i < 8; i++) {
    const int j = i * 512 + lane * 8;
    float4 w0 = *(const float4*)(w + j);
    float4 w1 = *(const float4*)(w + j + 4);
    float4 a0 = *(const float4*)(attn + j);
    float4 a1 = *(const float4*)(attn + j + 4);
    acc += w0.x * a0.x + w0.y * a0.y + w0.z * a0.z + w0.w * a0.w +
           w1.x * a1.x + w1.y * a1.y + w1.z * a1.z + w1.w * a1.w;
  }
#pragma unroll
  for (int off = 32; off > 0; off >>= 1) acc += __shfl_xor(acc, off);
  if (lane == 0) out[row] = acc;
}

extern "C" void kernel_launch(void* const* d_in, const int* in_sizes, int n_in,
                              void* d_out, int out_size, void* d_ws, size_t ws_size,
                              hipStream_t stream) {
  (void)in_sizes; (void)n_in; (void)out_size; (void)ws_size;
  const float* x      = (const float*)d_in[0];
  // d_in[1] = kv_sliding (unused by reference)
  const float* kvfull = (const float*)d_in[2];
  const float* wq     = (const float*)d_in[3];
  const float* wk     = (const float*)d_in[4];
  const float* wv     = (const float*)d_in[5];
  const float* wo     = (const float*)d_in[6];
  const int* cur_pos  = (const int*)d_in[7];
  // d_in[8] = ring_pos (unused by reference)
  float* out = (float*)d_out;
  float* ws = (float*)d_ws;

  qkv_gemv<<<(QDIM + 2 * HD) / 4, 256, 0, stream>>>(x, wq, wk, wv, ws + WS_QKV);
  attn_partial<<<NCHUNK, 256, 0, stream>>>(kvfull, ws, cur_pos, ws + WS_PART);
  attn_reduce<<<NHEADS * 16, 256, 0, stream>>>(ws + WS_PART, ws + WS_ATT);
  out_gemv<<<HIDDEN / 4, 256, 0, stream>>>(wo, ws + WS_ATT, out);
}